// Round 2
// baseline (159.661 us; speedup 1.0000x reference)
//
#include <hip/hip_runtime.h>
#include <math.h>

#define BB 4
#define CC 256
#define HWN 4096
#define NTOK 16384                 // BB*HWN
#define SCQ 0.09016844136f         // (1/sqrt(256)) * log2(e)

typedef __attribute__((ext_vector_type(8))) short short8;
typedef __attribute__((ext_vector_type(4))) float f32x4;
typedef __attribute__((ext_vector_type(2))) float f32x2;
typedef unsigned short ushort_t;

__device__ __forceinline__ ushort_t f2bf(float f) {
    unsigned int u = __float_as_uint(f);
    unsigned int r = (u + 0x7FFFu + ((u >> 16) & 1u)) >> 16;   // RNE
    return (ushort_t)r;
}
__device__ __forceinline__ unsigned int pack2(float a, float b) {
    return (unsigned int)f2bf(a) | ((unsigned int)f2bf(b) << 16);
}
__device__ __forceinline__ float fexp2(float x) {
#if __has_builtin(__builtin_amdgcn_exp2f)
    return __builtin_amdgcn_exp2f(x);     // single v_exp_f32, no libm fixups
#else
    return exp2f(x);
#endif
}

// ---------------------------------------------------------------------------
// Kernel 0: one-time weight prep. Converts q_w (pre-scaled by SCQ) and k_w
// to bf16 in workspace; zeroes den/nx/ny.
// ---------------------------------------------------------------------------
__global__ __launch_bounds__(256) void wprep_kernel(
    const float* __restrict__ q_w, const float* __restrict__ k_w,
    ushort_t* __restrict__ qwb, ushort_t* __restrict__ kwb,
    float* __restrict__ zbuf)
{
    int t = blockIdx.x * 256 + threadIdx.x;          // grid 64 -> 16384 threads
    float4 q4 = *(const float4*)&q_w[(size_t)t * 4];
    float4 k4 = *(const float4*)&k_w[(size_t)t * 4];
    unsigned long long qo = (unsigned long long)pack2(q4.x * SCQ, q4.y * SCQ)
                          | ((unsigned long long)pack2(q4.z * SCQ, q4.w * SCQ) << 32);
    unsigned long long ko = (unsigned long long)pack2(k4.x, k4.y)
                          | ((unsigned long long)pack2(k4.z, k4.w) << 32);
    *(unsigned long long*)&qwb[(size_t)t * 4] = qo;
    *(unsigned long long*)&kwb[(size_t)t * 4] = ko;
    zbuf[t] = 0.f; zbuf[t + NTOK] = 0.f; zbuf[t + 2 * NTOK] = 0.f;
}

// ---------------------------------------------------------------------------
// Fused projection. Block = 64 tokens x 64-d quarter. Grid 1024: quads at
// id, id+256, id+512, id+768 share (b,tt) and (256%8==0) the same XCD ->
// feature tile read once from HBM, 3x from L2. 3 blocks/CU (LDS 51.4KB).
// Phase 1: stage feature [256c x 64tok] fp32 -> bf16 LDS token-major.
// Phase 2 (no barriers): per wave, 16 d x 256 c MFMA for Q and K with
// pre-converted bf16 weights.
// ---------------------------------------------------------------------------
__global__ __launch_bounds__(256, 3) void proj_kernel(
    const float* __restrict__ feature,
    const ushort_t* __restrict__ qwb, const ushort_t* __restrict__ kwb,
    const float* __restrict__ q_bias, const float* __restrict__ k_bias,
    ushort_t* __restrict__ qb, ushort_t* __restrict__ kb)
{
    int id = blockIdx.x;
    int dh = id >> 8;            // 0..3: d-quarter
    id &= 255;
    int tt = id & 63;
    int b  = id >> 6;
    int tok0 = tt * 64;

    int t = threadIdx.x, w = t >> 6, lane = t & 63;
    int n16 = lane & 15, quad = lane >> 4;

    __shared__ float    lsA[64][69];    // [c-in-chunk][tok] fp32, stride 69
    __shared__ ushort_t lsB[64][264];   // [tok][c 0..255] bf16, stride 264

    const float* F = feature + (size_t)(b * CC) * HWN;

    int cl = t >> 2, tg = (t & 3) * 16;
    int tokw = t >> 2, c16 = (t & 3) * 16;

    for (int ch = 0; ch < 4; ch++) {
        const float* src = F + (size_t)(ch * 64 + cl) * HWN + tok0 + tg;
        *(float4*)&lsA[cl][tg]      = *(const float4*)(src);
        *(float4*)&lsA[cl][tg + 4]  = *(const float4*)(src + 4);
        *(float4*)&lsA[cl][tg + 8]  = *(const float4*)(src + 8);
        *(float4*)&lsA[cl][tg + 12] = *(const float4*)(src + 12);
        __syncthreads();
        #pragma unroll
        for (int jj = 0; jj < 8; jj++)
            *(unsigned int*)&lsB[tokw][ch * 64 + c16 + 2 * jj] =
                pack2(lsA[c16 + 2 * jj][tokw], lsA[c16 + 2 * jj + 1][tokw]);
        __syncthreads();
    }

    int d0 = dh * 64 + w * 16;          // one 16-d tile per wave
    f32x4 accq[4], acck[4];
    #pragma unroll
    for (int i = 0; i < 4; i++) {
        accq[i] = (f32x4){0.f, 0.f, 0.f, 0.f};
        acck[i] = (f32x4){0.f, 0.f, 0.f, 0.f};
    }
    #pragma unroll
    for (int kc = 0; kc < 8; kc++) {
        size_t off = (size_t)(d0 + n16) * CC + kc * 32 + quad * 8;
        short8 aq = *(const short8*)&qwb[off];
        short8 ak = *(const short8*)&kwb[off];
        #pragma unroll
        for (int tokt = 0; tokt < 4; tokt++) {
            short8 bf = *(const short8*)&lsB[tokt * 16 + n16][kc * 32 + quad * 8];
            accq[tokt] = __builtin_amdgcn_mfma_f32_16x16x32_bf16(aq, bf, accq[tokt], 0, 0, 0);
            acck[tokt] = __builtin_amdgcn_mfma_f32_16x16x32_bf16(ak, bf, acck[tokt], 0, 0, 0);
        }
    }
    float bqv[4], bkv[4];
    #pragma unroll
    for (int r = 0; r < 4; r++) {
        bqv[r] = q_bias[d0 + quad * 4 + r] * SCQ;
        bkv[r] = k_bias[d0 + quad * 4 + r];
    }
    #pragma unroll
    for (int tokt = 0; tokt < 4; tokt++) {
        size_t row = (size_t)(b * HWN + tok0 + tokt * 16 + n16) * CC + d0 + quad * 4;
        ushort4 oq, ok;
        oq.x = f2bf(accq[tokt][0] + bqv[0]); oq.y = f2bf(accq[tokt][1] + bqv[1]);
        oq.z = f2bf(accq[tokt][2] + bqv[2]); oq.w = f2bf(accq[tokt][3] + bqv[3]);
        ok.x = f2bf(acck[tokt][0] + bkv[0]); ok.y = f2bf(acck[tokt][1] + bkv[1]);
        ok.z = f2bf(acck[tokt][2] + bkv[2]); ok.w = f2bf(acck[tokt][3] + bkv[3]);
        *(ushort4*)&qb[row] = oq;
        *(ushort4*)&kb[row] = ok;
    }
}

// ---------------------------------------------------------------------------
// Flash MFMA attention. Block = (b, 128-q, 512-key range), 4 waves; each wave
// owns 32 q-rows (qf = 64 VGPR -> whole state fits 128 VGPR, no Q reload).
// Grid 1024, 4 blocks/CU all-resident. Bijective XCD swizzle keeps the 32
// qt-blocks sharing a K-range on one XCD. 32-key stages, double-buffered
// 2 x 16 KB XOR-swizzled LDS. Q pre-scaled by (1/16)*log2e => p = exp2(acc).
// ---------------------------------------------------------------------------
__global__ __launch_bounds__(256, 4) void attn_kernel(
    const ushort_t* __restrict__ qb, const ushort_t* __restrict__ kb,
    const float* __restrict__ flow,
    float* __restrict__ den_g, float* __restrict__ nx_g, float* __restrict__ ny_g)
{
    int id = (blockIdx.x & 7) * 128 + (blockIdx.x >> 3);   // 1024 = 8*128, bijective
    int qt = id & 31; id >>= 5;
    int sr = id & 7;  id >>= 3;
    int b = id;

    int t = threadIdx.x;
    int w = t >> 6, lane = t & 63;
    int n16 = lane & 15, quad = lane >> 4;

    int q0 = qt * 128 + w * 32;
    int s_beg = sr * 512;

    const ushort_t* Qb = qb + (size_t)b * HWN * CC;
    const ushort_t* Kb = kb + (size_t)b * HWN * CC;

    __shared__ __align__(16) ushort_t lk[2][8192];   // 2 x 16 KB swizzled K
    __shared__ float lflow[1024];                     // 512 vx + 512 vy

    const float* fx = flow + (size_t)b * 2 * HWN;
    const float* fy = fx + HWN;
    lflow[t]        = fx[s_beg + t];
    lflow[t + 256]  = fx[s_beg + t + 256];
    lflow[t + 512]  = fy[s_beg + t];
    lflow[t + 768]  = fy[s_beg + t + 256];

    short8 qf[2][8];
    #pragma unroll
    for (int tq = 0; tq < 2; tq++)
        #pragma unroll
        for (int c = 0; c < 8; c++)
            qf[tq][c] = *(const short8*)&Qb[(size_t)(q0 + tq * 16 + n16) * CC
                                            + c * 32 + quad * 8];

    // staging source offsets (XOR swizzle on 16B granules), loop-invariant
    int srcoff[4];
    #pragma unroll
    for (int i = 0; i < 4; i++) {
        int G = i * 256 + t;
        int r = G >> 5, j = G & 31;        // 32 rows x 32 granules
        srcoff[i] = (r * 32 + (j ^ r)) * 16;
    }
    int p16[8];
    #pragma unroll
    for (int c = 0; c < 8; c++)
        p16[c] = (((c * 4 + quad) ^ n16) & 31) * 16;

    f32x2 den[2][2], nxa[2][2], nya[2][2];
    #pragma unroll
    for (int tq = 0; tq < 2; tq++)
        #pragma unroll
        for (int j = 0; j < 2; j++) {
            den[tq][j] = (f32x2){0.f, 0.f};
            nxa[tq][j] = (f32x2){0.f, 0.f};
            nya[tq][j] = (f32x2){0.f, 0.f};
        }

    // prologue: stage tile 0 into buffer 0
    {
        const char* gsrc = (const char*)(Kb + (size_t)s_beg * CC);
        char* ldst = (char*)lk[0] + t * 16;
        #pragma unroll
        for (int i = 0; i < 4; i++)
            __builtin_amdgcn_global_load_lds(
                (const __attribute__((address_space(1))) unsigned int*)(gsrc + srcoff[i]),
                (__attribute__((address_space(3))) unsigned int*)(ldst + i * 4096),
                16, 0, 0);
    }

    for (int st = 0; st < 16; st++) {
        __syncthreads();   // buffer st&1 staged; prior reads of other buffer done
        if (st + 1 < 16) {
            const char* gsrc = (const char*)(Kb + (size_t)(s_beg + (st + 1) * 32) * CC);
            char* ldst = (char*)lk[(st + 1) & 1] + t * 16;
            #pragma unroll
            for (int i = 0; i < 4; i++)
                __builtin_amdgcn_global_load_lds(
                    (const __attribute__((address_space(1))) unsigned int*)(gsrc + srcoff[i]),
                    (__attribute__((address_space(3))) unsigned int*)(ldst + i * 4096),
                    16, 0, 0);
        }
        const char* base = (const char*)lk[st & 1];

        #pragma unroll
        for (int bt = 0; bt < 2; bt++) {
            int rbase = (bt * 16 + n16) * 512;
            int x16   = bt ? 256 : 0;
            f32x4 a0 = {0.f, 0.f, 0.f, 0.f};
            f32x4 a1 = {0.f, 0.f, 0.f, 0.f};
            #pragma unroll
            for (int c = 0; c < 8; c++) {
                short8 kf = *(const short8*)(base + rbase + (p16[c] ^ x16));
                a0 = __builtin_amdgcn_mfma_f32_16x16x32_bf16(qf[0][c], kf, a0, 0, 0, 0);
                a1 = __builtin_amdgcn_mfma_f32_16x16x32_bf16(qf[1][c], kf, a1, 0, 0, 0);
            }
            int sidx = st * 32 + bt * 16 + n16;
            float vx = lflow[sidx];
            float vy = lflow[512 + sidx];
            f32x2 vx2 = (f32x2){vx, vx};
            f32x2 vy2 = (f32x2){vy, vy};
            #pragma unroll
            for (int tq = 0; tq < 2; tq++) {
                f32x4 a = (tq == 0) ? a0 : a1;
                f32x2 p0 = (f32x2){fexp2(a[0]), fexp2(a[1])};
                f32x2 p1 = (f32x2){fexp2(a[2]), fexp2(a[3])};
                den[tq][0] += p0;
                den[tq][1] += p1;
                nxa[tq][0] = __builtin_elementwise_fma(p0, vx2, nxa[tq][0]);
                nxa[tq][1] = __builtin_elementwise_fma(p1, vx2, nxa[tq][1]);
                nya[tq][0] = __builtin_elementwise_fma(p0, vy2, nya[tq][0]);
                nya[tq][1] = __builtin_elementwise_fma(p1, vy2, nya[tq][1]);
            }
        }
    }

    #pragma unroll
    for (int tq = 0; tq < 2; tq++)
        #pragma unroll
        for (int j = 0; j < 2; j++)
            #pragma unroll
            for (int e = 0; e < 2; e++) {
                float dv = den[tq][j][e];
                float xv = nxa[tq][j][e];
                float yv = nya[tq][j][e];
                #pragma unroll
                for (int off = 8; off >= 1; off >>= 1) {
                    dv += __shfl_down(dv, off, 16);
                    xv += __shfl_down(xv, off, 16);
                    yv += __shfl_down(yv, off, 16);
                }
                if (n16 == 0) {
                    int r = j * 2 + e;
                    int qrow = q0 + tq * 16 + quad * 4 + r;
                    int gi = b * HWN + qrow;
                    atomicAdd(&den_g[gi], dv);
                    atomicAdd(&nx_g[gi],  xv);
                    atomicAdd(&ny_g[gi],  yv);
                }
            }
}

// ---------------------------------------------------------------------------
__global__ __launch_bounds__(256) void finalize_kernel(
    const float* __restrict__ den_g, const float* __restrict__ nx_g,
    const float* __restrict__ ny_g, float* __restrict__ out)
{
    int idx = blockIdx.x * 256 + threadIdx.x;  // b*HW + n
    int b = idx >> 12, n = idx & 4095;
    float inv = 1.0f / den_g[idx];
    out[(size_t)b * 2 * HWN + n]       = nx_g[idx] * inv;
    out[(size_t)b * 2 * HWN + HWN + n] = ny_g[idx] * inv;
}

extern "C" void kernel_launch(void* const* d_in, const int* in_sizes, int n_in,
                              void* d_out, int out_size, void* d_ws, size_t ws_size,
                              hipStream_t stream) {
    const float* feature = (const float*)d_in[0];
    const float* flow    = (const float*)d_in[1];
    const float* q_w     = (const float*)d_in[2];
    const float* q_b     = (const float*)d_in[3];
    const float* k_w     = (const float*)d_in[4];
    const float* k_b     = (const float*)d_in[5];
    float* out = (float*)d_out;

    ushort_t* qbuf = (ushort_t*)d_ws;                     // [NTOK][CC] bf16
    ushort_t* kbuf = qbuf + (size_t)NTOK * CC;            // [NTOK][CC] bf16
    float* den = (float*)(kbuf + (size_t)NTOK * CC);      // [NTOK]
    float* nx  = den + NTOK;
    float* ny  = nx + NTOK;
    ushort_t* qwb = (ushort_t*)(ny + NTOK);               // [CC][CC] bf16 (pre-scaled)
    ushort_t* kwb = qwb + (size_t)CC * CC;                // [CC][CC] bf16

    wprep_kernel<<<64, 256, 0, stream>>>(q_w, k_w, qwb, kwb, den); // + zero den/nx/ny
    proj_kernel<<<1024, 256, 0, stream>>>(feature, qwb, kwb, q_b, k_b, qbuf, kbuf);
    attn_kernel<<<1024, 256, 0, stream>>>(qbuf, kbuf, flow, den, nx, ny);
    finalize_kernel<<<64, 256, 0, stream>>>(den, nx, ny, out);
}

// Round 3
// 149.000 us; speedup vs baseline: 1.0716x; 1.0716x over previous
//
#include <hip/hip_runtime.h>
#include <math.h>

#define BB 4
#define CC 256
#define HWN 4096
#define NTOK 16384                 // BB*HWN
#define SCQ 0.09016844136f         // (1/sqrt(256)) * log2(e)

typedef __attribute__((ext_vector_type(8))) short short8;
typedef __attribute__((ext_vector_type(4))) float f32x4;
typedef __attribute__((ext_vector_type(2))) float f32x2;
typedef unsigned short ushort_t;

__device__ __forceinline__ ushort_t f2bf(float f) {
    unsigned int u = __float_as_uint(f);
    unsigned int r = (u + 0x7FFFu + ((u >> 16) & 1u)) >> 16;   // RNE
    return (ushort_t)r;
}
__device__ __forceinline__ unsigned int pack2(float a, float b) {
    return (unsigned int)f2bf(a) | ((unsigned int)f2bf(b) << 16);
}
__device__ __forceinline__ float fexp2(float x) {
#if __has_builtin(__builtin_amdgcn_exp2f)
    return __builtin_amdgcn_exp2f(x);     // single v_exp_f32
#else
    return exp2f(x);
#endif
}

// ---------------------------------------------------------------------------
// Kernel 0: prep. Blocks 0..1023: transpose feature [C][HW] fp32 -> fbuf
// [HW][C] bf16 (64x64 tiles via LDS; done ONCE chip-wide so proj never
// re-transposes). Blocks 1024..1087: convert q_w (pre-scaled by SCQ) and k_w
// to bf16 and zero den/nx/ny.
// ---------------------------------------------------------------------------
__global__ __launch_bounds__(256) void prep_kernel(
    const float* __restrict__ feature,
    const float* __restrict__ q_w, const float* __restrict__ k_w,
    ushort_t* __restrict__ fbuf,
    ushort_t* __restrict__ qwb, ushort_t* __restrict__ kwb,
    float* __restrict__ zbuf)
{
    int bid = blockIdx.x;
    int tid = threadIdx.x;

    if (bid >= 1024) {                       // weight convert + zero
        int t = (bid - 1024) * 256 + tid;    // 0..16383
        float4 q4 = *(const float4*)&q_w[(size_t)t * 4];
        float4 k4 = *(const float4*)&k_w[(size_t)t * 4];
        unsigned long long qo = (unsigned long long)pack2(q4.x * SCQ, q4.y * SCQ)
                              | ((unsigned long long)pack2(q4.z * SCQ, q4.w * SCQ) << 32);
        unsigned long long ko = (unsigned long long)pack2(k4.x, k4.y)
                              | ((unsigned long long)pack2(k4.z, k4.w) << 32);
        *(unsigned long long*)&qwb[(size_t)t * 4] = qo;
        *(unsigned long long*)&kwb[(size_t)t * 4] = ko;
        zbuf[t] = 0.f; zbuf[t + NTOK] = 0.f; zbuf[t + 2 * NTOK] = 0.f;
        return;
    }

    // transpose tile: b (0..3), cch (0..3), nch (0..63)
    int b   = bid >> 8;
    int rem = bid & 255;
    int cch = rem >> 6;
    int nch = rem & 63;

    __shared__ float lsA[64][69];            // [c][n] fp32, stride 69

    int cl = tid >> 2, tg = (tid & 3) * 16;
    const float* src = feature + (size_t)(b * CC + cch * 64 + cl) * HWN + nch * 64 + tg;
    *(float4*)&lsA[cl][tg]      = *(const float4*)(src);
    *(float4*)&lsA[cl][tg + 4]  = *(const float4*)(src + 4);
    *(float4*)&lsA[cl][tg + 8]  = *(const float4*)(src + 8);
    *(float4*)&lsA[cl][tg + 12] = *(const float4*)(src + 12);
    __syncthreads();

    int tokw = tid >> 2, c16 = (tid & 3) * 16;
    unsigned int u[8];
    #pragma unroll
    for (int j = 0; j < 8; j++)
        u[j] = pack2(lsA[c16 + 2 * j][tokw], lsA[c16 + 2 * j + 1][tokw]);
    size_t orow = (size_t)(b * HWN + nch * 64 + tokw) * CC + cch * 64 + c16;
    *(uint4*)&fbuf[orow]     = *(uint4*)&u[0];
    *(uint4*)&fbuf[orow + 8] = *(uint4*)&u[4];
}

// ---------------------------------------------------------------------------
// Projection v3: pure register GEMM, no LDS, no barriers. Block = 64 tokens x
// 64-d quarter, 4 waves = one 16-d tile each. A-frags (q+k weights, 16 short8
// = 64 VGPR) held in registers; B-frags (feature, token-major bf16) streamed
// straight from L2. dh siblings (id, id+256, ...) land on the same XCD
// (256%8==0) so fbuf rows are L2-shared. ~122 VGPR -> 4 blocks/CU.
// ---------------------------------------------------------------------------
__global__ __launch_bounds__(256, 2) void proj_kernel(
    const ushort_t* __restrict__ fbuf,
    const ushort_t* __restrict__ qwb, const ushort_t* __restrict__ kwb,
    const float* __restrict__ q_bias, const float* __restrict__ k_bias,
    ushort_t* __restrict__ qb, ushort_t* __restrict__ kb)
{
    int id = blockIdx.x;
    int dh = id >> 8;                 // 0..3 d-quarter
    int inner = id & 255;
    int b   = inner & 3;
    int tch = inner >> 2;             // 0..63
    int tok0 = tch * 64;

    int t = threadIdx.x, w = t >> 6, lane = t & 63;
    int n16 = lane & 15, quad = lane >> 4;

    int d0 = dh * 64 + w * 16;

    short8 aq[8], ak[8];
    #pragma unroll
    for (int kc = 0; kc < 8; kc++) {
        size_t off = (size_t)(d0 + n16) * CC + kc * 32 + quad * 8;
        aq[kc] = *(const short8*)&qwb[off];
        ak[kc] = *(const short8*)&kwb[off];
    }
    float bqv[4], bkv[4];
    #pragma unroll
    for (int r = 0; r < 4; r++) {
        bqv[r] = q_bias[d0 + quad * 4 + r] * SCQ;
        bkv[r] = k_bias[d0 + quad * 4 + r];
    }

    #pragma unroll
    for (int tokt = 0; tokt < 4; tokt++) {
        size_t trow = (size_t)(b * HWN + tok0 + tokt * 16 + n16) * CC;
        short8 bf[8];
        #pragma unroll
        for (int kc = 0; kc < 8; kc++)
            bf[kc] = *(const short8*)&fbuf[trow + kc * 32 + quad * 8];
        f32x4 accq = (f32x4){0.f, 0.f, 0.f, 0.f};
        f32x4 acck = (f32x4){0.f, 0.f, 0.f, 0.f};
        #pragma unroll
        for (int kc = 0; kc < 8; kc++) {
            accq = __builtin_amdgcn_mfma_f32_16x16x32_bf16(aq[kc], bf[kc], accq, 0, 0, 0);
            acck = __builtin_amdgcn_mfma_f32_16x16x32_bf16(ak[kc], bf[kc], acck, 0, 0, 0);
        }
        size_t row = trow + d0 + quad * 4;
        ushort4 oq, ok;
        oq.x = f2bf(accq[0] + bqv[0]); oq.y = f2bf(accq[1] + bqv[1]);
        oq.z = f2bf(accq[2] + bqv[2]); oq.w = f2bf(accq[3] + bqv[3]);
        ok.x = f2bf(acck[0] + bkv[0]); ok.y = f2bf(acck[1] + bkv[1]);
        ok.z = f2bf(acck[2] + bkv[2]); ok.w = f2bf(acck[3] + bkv[3]);
        *(ushort4*)&qb[row] = oq;
        *(ushort4*)&kb[row] = ok;
    }
}

// ---------------------------------------------------------------------------
// Flash MFMA attention. Block = (b, 128-q, 512-key range), 4 waves; each wave
// owns 32 q-rows (qf = 64 VGPR; total ~118 VGPR fits the 128 cap -> NO
// scratch spill; launch_bounds arg 2 because cap == 256/arg empirically).
// Grid 1024, 4 blocks/CU by LDS (36.9KB). Bijective XCD swizzle keeps the 32
// qt-blocks sharing a K-range on one XCD. 32-key stages, double-buffered
// 2 x 16 KB XOR-swizzled LDS. Q pre-scaled by (1/16)*log2e => p = exp2(acc).
// ---------------------------------------------------------------------------
__global__ __launch_bounds__(256, 2) void attn_kernel(
    const ushort_t* __restrict__ qb, const ushort_t* __restrict__ kb,
    const float* __restrict__ flow,
    float* __restrict__ den_g, float* __restrict__ nx_g, float* __restrict__ ny_g)
{
    int id = (blockIdx.x & 7) * 128 + (blockIdx.x >> 3);   // 1024 = 8*128, bijective
    int qt = id & 31; id >>= 5;
    int sr = id & 7;  id >>= 3;
    int b = id;

    int t = threadIdx.x;
    int w = t >> 6, lane = t & 63;
    int n16 = lane & 15, quad = lane >> 4;

    int q0 = qt * 128 + w * 32;
    int s_beg = sr * 512;

    const ushort_t* Qb = qb + (size_t)b * HWN * CC;
    const ushort_t* Kb = kb + (size_t)b * HWN * CC;

    __shared__ __align__(16) ushort_t lk[2][8192];   // 2 x 16 KB swizzled K
    __shared__ float lflow[1024];                     // 512 vx + 512 vy

    const float* fx = flow + (size_t)b * 2 * HWN;
    const float* fy = fx + HWN;
    lflow[t]        = fx[s_beg + t];
    lflow[t + 256]  = fx[s_beg + t + 256];
    lflow[t + 512]  = fy[s_beg + t];
    lflow[t + 768]  = fy[s_beg + t + 256];

    short8 qf[2][8];
    #pragma unroll
    for (int tq = 0; tq < 2; tq++)
        #pragma unroll
        for (int c = 0; c < 8; c++)
            qf[tq][c] = *(const short8*)&Qb[(size_t)(q0 + tq * 16 + n16) * CC
                                            + c * 32 + quad * 8];

    // staging source offsets (XOR swizzle on 16B granules), loop-invariant
    int srcoff[4];
    #pragma unroll
    for (int i = 0; i < 4; i++) {
        int G = i * 256 + t;
        int r = G >> 5, j = G & 31;        // 32 rows x 32 granules
        srcoff[i] = (r * 32 + (j ^ r)) * 16;
    }
    int p16[8];
    #pragma unroll
    for (int c = 0; c < 8; c++)
        p16[c] = (((c * 4 + quad) ^ n16) & 31) * 16;

    f32x2 den[2][2], nxa[2][2], nya[2][2];
    #pragma unroll
    for (int tq = 0; tq < 2; tq++)
        #pragma unroll
        for (int j = 0; j < 2; j++) {
            den[tq][j] = (f32x2){0.f, 0.f};
            nxa[tq][j] = (f32x2){0.f, 0.f};
            nya[tq][j] = (f32x2){0.f, 0.f};
        }

    // prologue: stage tile 0 into buffer 0
    {
        const char* gsrc = (const char*)(Kb + (size_t)s_beg * CC);
        char* ldst = (char*)lk[0] + t * 16;
        #pragma unroll
        for (int i = 0; i < 4; i++)
            __builtin_amdgcn_global_load_lds(
                (const __attribute__((address_space(1))) unsigned int*)(gsrc + srcoff[i]),
                (__attribute__((address_space(3))) unsigned int*)(ldst + i * 4096),
                16, 0, 0);
    }

    for (int st = 0; st < 16; st++) {
        __syncthreads();   // buffer st&1 staged; prior reads of other buffer done
        if (st + 1 < 16) {
            const char* gsrc = (const char*)(Kb + (size_t)(s_beg + (st + 1) * 32) * CC);
            char* ldst = (char*)lk[(st + 1) & 1] + t * 16;
            #pragma unroll
            for (int i = 0; i < 4; i++)
                __builtin_amdgcn_global_load_lds(
                    (const __attribute__((address_space(1))) unsigned int*)(gsrc + srcoff[i]),
                    (__attribute__((address_space(3))) unsigned int*)(ldst + i * 4096),
                    16, 0, 0);
        }
        const char* base = (const char*)lk[st & 1];

        #pragma unroll
        for (int bt = 0; bt < 2; bt++) {
            int rbase = (bt * 16 + n16) * 512;
            int x16   = bt ? 256 : 0;
            f32x4 a0 = {0.f, 0.f, 0.f, 0.f};
            f32x4 a1 = {0.f, 0.f, 0.f, 0.f};
            #pragma unroll
            for (int c = 0; c < 8; c++) {
                short8 kf = *(const short8*)(base + rbase + (p16[c] ^ x16));
                a0 = __builtin_amdgcn_mfma_f32_16x16x32_bf16(qf[0][c], kf, a0, 0, 0, 0);
                a1 = __builtin_amdgcn_mfma_f32_16x16x32_bf16(qf[1][c], kf, a1, 0, 0, 0);
            }
            int sidx = st * 32 + bt * 16 + n16;
            float vx = lflow[sidx];
            float vy = lflow[512 + sidx];
            f32x2 vx2 = (f32x2){vx, vx};
            f32x2 vy2 = (f32x2){vy, vy};
            #pragma unroll
            for (int tq = 0; tq < 2; tq++) {
                f32x4 a = (tq == 0) ? a0 : a1;
                f32x2 p0 = (f32x2){fexp2(a[0]), fexp2(a[1])};
                f32x2 p1 = (f32x2){fexp2(a[2]), fexp2(a[3])};
                den[tq][0] += p0;
                den[tq][1] += p1;
                nxa[tq][0] = __builtin_elementwise_fma(p0, vx2, nxa[tq][0]);
                nxa[tq][1] = __builtin_elementwise_fma(p1, vx2, nxa[tq][1]);
                nya[tq][0] = __builtin_elementwise_fma(p0, vy2, nya[tq][0]);
                nya[tq][1] = __builtin_elementwise_fma(p1, vy2, nya[tq][1]);
            }
        }
    }

    #pragma unroll
    for (int tq = 0; tq < 2; tq++)
        #pragma unroll
        for (int j = 0; j < 2; j++)
            #pragma unroll
            for (int e = 0; e < 2; e++) {
                float dv = den[tq][j][e];
                float xv = nxa[tq][j][e];
                float yv = nya[tq][j][e];
                #pragma unroll
                for (int off = 8; off >= 1; off >>= 1) {
                    dv += __shfl_down(dv, off, 16);
                    xv += __shfl_down(xv, off, 16);
                    yv += __shfl_down(yv, off, 16);
                }
                if (n16 == 0) {
                    int r = j * 2 + e;
                    int qrow = q0 + tq * 16 + quad * 4 + r;
                    int gi = b * HWN + qrow;
                    atomicAdd(&den_g[gi], dv);
                    atomicAdd(&nx_g[gi],  xv);
                    atomicAdd(&ny_g[gi],  yv);
                }
            }
}

// ---------------------------------------------------------------------------
__global__ __launch_bounds__(256) void finalize_kernel(
    const float* __restrict__ den_g, const float* __restrict__ nx_g,
    const float* __restrict__ ny_g, float* __restrict__ out)
{
    int idx = blockIdx.x * 256 + threadIdx.x;  // b*HW + n
    int b = idx >> 12, n = idx & 4095;
    float inv = 1.0f / den_g[idx];
    out[(size_t)b * 2 * HWN + n]       = nx_g[idx] * inv;
    out[(size_t)b * 2 * HWN + HWN + n] = ny_g[idx] * inv;
}

extern "C" void kernel_launch(void* const* d_in, const int* in_sizes, int n_in,
                              void* d_out, int out_size, void* d_ws, size_t ws_size,
                              hipStream_t stream) {
    const float* feature = (const float*)d_in[0];
    const float* flow    = (const float*)d_in[1];
    const float* q_w     = (const float*)d_in[2];
    const float* q_b     = (const float*)d_in[3];
    const float* k_w     = (const float*)d_in[4];
    const float* k_b     = (const float*)d_in[5];
    float* out = (float*)d_out;

    ushort_t* qbuf = (ushort_t*)d_ws;                     // [NTOK][CC] bf16
    ushort_t* kbuf = qbuf + (size_t)NTOK * CC;            // [NTOK][CC] bf16
    float* den = (float*)(kbuf + (size_t)NTOK * CC);      // [NTOK]
    float* nx  = den + NTOK;
    float* ny  = nx + NTOK;
    ushort_t* qwb = (ushort_t*)(ny + NTOK);               // [CC][CC] bf16 (pre-scaled)
    ushort_t* kwb = qwb + (size_t)CC * CC;                // [CC][CC] bf16
    ushort_t* fbuf = kwb + (size_t)CC * CC;               // [NTOK][CC] bf16 token-major

    prep_kernel<<<1088, 256, 0, stream>>>(feature, q_w, k_w, fbuf, qwb, kwb, den);
    proj_kernel<<<1024, 256, 0, stream>>>(fbuf, qwb, kwb, q_b, k_b, qbuf, kbuf);
    attn_kernel<<<1024, 256, 0, stream>>>(qbuf, kbuf, flow, den, nx, ny);
    finalize_kernel<<<64, 256, 0, stream>>>(den, nx, ny, out);
}

// Round 4
// 146.054 us; speedup vs baseline: 1.0932x; 1.0202x over previous
//
#include <hip/hip_runtime.h>
#include <math.h>

#define BB 4
#define CC 256
#define HWN 4096
#define NTOK 16384                 // BB*HWN
#define SCQ 0.09016844136f         // (1/sqrt(256)) * log2(e)

typedef __attribute__((ext_vector_type(8))) short short8;
typedef __attribute__((ext_vector_type(4))) float f32x4;
typedef unsigned short ushort_t;

__device__ __forceinline__ ushort_t f2bf(float f) {
    unsigned int u = __float_as_uint(f);
    unsigned int r = (u + 0x7FFFu + ((u >> 16) & 1u)) >> 16;   // RNE
    return (ushort_t)r;
}
__device__ __forceinline__ unsigned int pack2(float a, float b) {
    return (unsigned int)f2bf(a) | ((unsigned int)f2bf(b) << 16);
}
__device__ __forceinline__ float fexp2(float x) {
#if __has_builtin(__builtin_amdgcn_exp2f)
    return __builtin_amdgcn_exp2f(x);     // single v_exp_f32
#else
    return exp2f(x);
#endif
}

// ---------------------------------------------------------------------------
// Kernel 0: prep. Blocks 0..1023: transpose feature [C][HW] fp32 -> fbuf
// [HW][C] bf16 (64x64 tiles via LDS). Blocks 1024..1087: convert q_w
// (pre-scaled by SCQ) and k_w to bf16; zero den/nx/ny.
// ---------------------------------------------------------------------------
__global__ __launch_bounds__(256) void prep_kernel(
    const float* __restrict__ feature,
    const float* __restrict__ q_w, const float* __restrict__ k_w,
    ushort_t* __restrict__ fbuf,
    ushort_t* __restrict__ qwb, ushort_t* __restrict__ kwb,
    float* __restrict__ zbuf)
{
    int bid = blockIdx.x;
    int tid = threadIdx.x;

    if (bid >= 1024) {                       // weight convert + zero
        int t = (bid - 1024) * 256 + tid;    // 0..16383
        float4 q4 = *(const float4*)&q_w[(size_t)t * 4];
        float4 k4 = *(const float4*)&k_w[(size_t)t * 4];
        unsigned long long qo = (unsigned long long)pack2(q4.x * SCQ, q4.y * SCQ)
                              | ((unsigned long long)pack2(q4.z * SCQ, q4.w * SCQ) << 32);
        unsigned long long ko = (unsigned long long)pack2(k4.x, k4.y)
                              | ((unsigned long long)pack2(k4.z, k4.w) << 32);
        *(unsigned long long*)&qwb[(size_t)t * 4] = qo;
        *(unsigned long long*)&kwb[(size_t)t * 4] = ko;
        zbuf[t] = 0.f; zbuf[t + NTOK] = 0.f; zbuf[t + 2 * NTOK] = 0.f;
        return;
    }

    // transpose tile: b (0..3), cch (0..3), nch (0..63)
    int b   = bid >> 8;
    int rem = bid & 255;
    int cch = rem >> 6;
    int nch = rem & 63;

    __shared__ float lsA[64][69];            // [c][n] fp32, stride 69

    int cl = tid >> 2, tg = (tid & 3) * 16;
    const float* src = feature + (size_t)(b * CC + cch * 64 + cl) * HWN + nch * 64 + tg;
    *(float4*)&lsA[cl][tg]      = *(const float4*)(src);
    *(float4*)&lsA[cl][tg + 4]  = *(const float4*)(src + 4);
    *(float4*)&lsA[cl][tg + 8]  = *(const float4*)(src + 8);
    *(float4*)&lsA[cl][tg + 12] = *(const float4*)(src + 12);
    __syncthreads();

    int tokw = tid >> 2, c16 = (tid & 3) * 16;
    unsigned int u[8];
    #pragma unroll
    for (int j = 0; j < 8; j++)
        u[j] = pack2(lsA[c16 + 2 * j][tokw], lsA[c16 + 2 * j + 1][tokw]);
    size_t orow = (size_t)(b * HWN + nch * 64 + tokw) * CC + cch * 64 + c16;
    *(uint4*)&fbuf[orow]     = *(uint4*)&u[0];
    *(uint4*)&fbuf[orow + 8] = *(uint4*)&u[4];
}

// ---------------------------------------------------------------------------
// Projection: register GEMM, no LDS/barriers. Block = 64 tokens x 64-d
// quarter. OUTPUT IS FRAGMENT-GRANULE MAJOR: granule g(b,tile16,kc,quad,n16)
// = X[tile*16+n16][kc*32+quad*8 .. +8] stored at byte ((b*256+tile)*512 +
// kc*64 + quad*16 + n16)*16. Each proj lane (pq,n16) owns 4 consecutive d
// = half a granule -> 8B stores, 512B contiguous per wave instruction.
// ---------------------------------------------------------------------------
__global__ __launch_bounds__(256, 2) void proj_kernel(
    const ushort_t* __restrict__ fbuf,
    const ushort_t* __restrict__ qwb, const ushort_t* __restrict__ kwb,
    const float* __restrict__ q_bias, const float* __restrict__ k_bias,
    ushort_t* __restrict__ qb, ushort_t* __restrict__ kb)
{
    int id = blockIdx.x;
    int dh = id >> 8;                 // 0..3 d-quarter
    int inner = id & 255;
    int b   = inner & 3;
    int tch = inner >> 2;             // 0..63
    int tok0 = tch * 64;

    int t = threadIdx.x, w = t >> 6, lane = t & 63;
    int n16 = lane & 15, quad = lane >> 4;

    int d0 = dh * 64 + w * 16;

    short8 aq[8], ak[8];
    #pragma unroll
    for (int kc = 0; kc < 8; kc++) {
        size_t off = (size_t)(d0 + n16) * CC + kc * 32 + quad * 8;
        aq[kc] = *(const short8*)&qwb[off];
        ak[kc] = *(const short8*)&kwb[off];
    }
    float bqv[4], bkv[4];
    #pragma unroll
    for (int r = 0; r < 4; r++) {
        bqv[r] = q_bias[d0 + quad * 4 + r] * SCQ;
        bkv[r] = k_bias[d0 + quad * 4 + r];
    }

    // fragment-granule store indices (loop-invariant parts)
    int kcq   = d0 >> 5;                          // kc of the granule
    int quadA = ((d0 >> 4) & 1) * 2 + (quad >> 1);// quad of the granule
    int halfo = quad & 1;                         // which 8B half

    #pragma unroll
    for (int tokt = 0; tokt < 4; tokt++) {
        size_t trow = (size_t)(b * HWN + tok0 + tokt * 16 + n16) * CC;
        short8 bf[8];
        #pragma unroll
        for (int kc = 0; kc < 8; kc++)
            bf[kc] = *(const short8*)&fbuf[trow + kc * 32 + quad * 8];
        f32x4 accq = (f32x4){0.f, 0.f, 0.f, 0.f};
        f32x4 acck = (f32x4){0.f, 0.f, 0.f, 0.f};
        #pragma unroll
        for (int kc = 0; kc < 8; kc++) {
            accq = __builtin_amdgcn_mfma_f32_16x16x32_bf16(aq[kc], bf[kc], accq, 0, 0, 0);
            acck = __builtin_amdgcn_mfma_f32_16x16x32_bf16(ak[kc], bf[kc], acck, 0, 0, 0);
        }
        ushort4 oq, ok;
        oq.x = f2bf(accq[0] + bqv[0]); oq.y = f2bf(accq[1] + bqv[1]);
        oq.z = f2bf(accq[2] + bqv[2]); oq.w = f2bf(accq[3] + bqv[3]);
        ok.x = f2bf(acck[0] + bkv[0]); ok.y = f2bf(acck[1] + bkv[1]);
        ok.z = f2bf(acck[2] + bkv[2]); ok.w = f2bf(acck[3] + bkv[3]);
        int tt_tile = tch * 4 + tokt;
        size_t gbyte = (((size_t)(b * 256 + tt_tile) * 512) + kcq * 64 + quadA * 16 + n16) * 16
                       + halfo * 8;
        *(ushort4*)((char*)qb + gbyte) = oq;
        *(ushort4*)((char*)kb + gbyte) = ok;
    }
}

// ---------------------------------------------------------------------------
// Barrier-free flash attention. Block = (b, 128-q, 512-key), 4 waves =
// (q-half x key-half); wave = 64 q x 256 keys. Q (fragment-major) staged
// linearly to LDS once (single prologue barrier), read as B-frags at
// lane-contiguous stride-16B (conflict-free, no swizzle). K streamed
// L2->registers per 32-key round, coalesced 1KB/inst. mfma(K,Q) -> lane owns
// 4 key-rows x 1 q-col => den/nx/ny = 12 regs, flow via LDS broadcast.
// NO barriers in the K-loop; merge across waves/blocks via atomics.
// ---------------------------------------------------------------------------
__global__ __launch_bounds__(256, 2) void attn_kernel(
    const ushort_t* __restrict__ qb, const ushort_t* __restrict__ kb,
    const float* __restrict__ flow,
    float* __restrict__ den_g, float* __restrict__ nx_g, float* __restrict__ ny_g)
{
    int id = (blockIdx.x & 7) * 128 + (blockIdx.x >> 3);   // bijective XCD swizzle
    int qt = id & 31; id >>= 5;
    int sr = id & 7;  id >>= 3;
    int b = id;

    int t = threadIdx.x;
    int w = t >> 6, lane = t & 63;
    int n16 = lane & 15, quad = lane >> 4;
    int qhalf = w & 1, khalf = w >> 1;

    int q0 = qt * 128;
    int s_beg = sr * 512;

    __shared__ __align__(16) ushort_t qlds[32768];   // 64 KB: 8 q-tiles, frag-major
    __shared__ float lflow[1024];                    // 512 vx + 512 vy

    const float* fx = flow + (size_t)b * 2 * HWN;
    const float* fy = fx + HWN;
    lflow[t]        = fx[s_beg + t];
    lflow[t + 256]  = fx[s_beg + t + 256];
    lflow[t + 512]  = fy[s_beg + t];
    lflow[t + 768]  = fy[s_beg + t + 256];

    // stage Q block (8 tiles x 512 granules x 16B = 64KB), linear copy
    {
        const char* qsrc = (const char*)qb + ((size_t)(b * 256 + (q0 >> 4)) * 512) * 16;
        char* qdst = (char*)qlds;
        #pragma unroll
        for (int i = 0; i < 16; i++)
            __builtin_amdgcn_global_load_lds(
                (const __attribute__((address_space(1))) unsigned int*)(qsrc + (i * 256 + t) * 16),
                (__attribute__((address_space(3))) unsigned int*)(qdst + (i * 256 + t) * 16),
                16, 0, 0);
    }
    __syncthreads();   // only barrier: Q + flow staged

    // K granule base for this wave's 256-key range
    const char* kbase = (const char*)kb
        + ((size_t)(b * 256 + (s_beg >> 4) + khalf * 16) * 512 + lane) * 16;
    const char* qldsb = (const char*)qlds + (size_t)qhalf * 4 * 8192 + (size_t)lane * 16;

    float den[4], nxa[4], nya[4];
    #pragma unroll
    for (int i = 0; i < 4; i++) { den[i] = 0.f; nxa[i] = 0.f; nya[i] = 0.f; }

    for (int round = 0; round < 8; round++) {
        short8 kf0[8], kf1[8];
        #pragma unroll
        for (int kc = 0; kc < 8; kc++) {
            kf0[kc] = *(const short8*)(kbase + (round * 2 + 0) * 8192 + kc * 1024);
            kf1[kc] = *(const short8*)(kbase + (round * 2 + 1) * 8192 + kc * 1024);
        }
        int klbase = khalf * 256 + round * 32 + quad * 4;
        f32x4 vx0 = *(const f32x4*)&lflow[klbase];
        f32x4 vx1 = *(const f32x4*)&lflow[klbase + 16];
        f32x4 vy0 = *(const f32x4*)&lflow[512 + klbase];
        f32x4 vy1 = *(const f32x4*)&lflow[512 + klbase + 16];

        #pragma unroll
        for (int qtl = 0; qtl < 4; qtl++) {
            f32x4 a0 = (f32x4){0.f, 0.f, 0.f, 0.f};
            f32x4 a1 = (f32x4){0.f, 0.f, 0.f, 0.f};
            #pragma unroll
            for (int kc = 0; kc < 8; kc++) {
                short8 qf = *(const short8*)(qldsb + qtl * 8192 + kc * 1024);
                a0 = __builtin_amdgcn_mfma_f32_16x16x32_bf16(kf0[kc], qf, a0, 0, 0, 0);
                a1 = __builtin_amdgcn_mfma_f32_16x16x32_bf16(kf1[kc], qf, a1, 0, 0, 0);
            }
            float d_ = 0.f, x_ = 0.f, y_ = 0.f;
            #pragma unroll
            for (int r = 0; r < 4; r++) {
                float p0 = fexp2(a0[r]);
                float p1 = fexp2(a1[r]);
                d_ += p0 + p1;
                x_ = fmaf(p0, vx0[r], x_); x_ = fmaf(p1, vx1[r], x_);
                y_ = fmaf(p0, vy0[r], y_); y_ = fmaf(p1, vy1[r], y_);
            }
            den[qtl] += d_; nxa[qtl] += x_; nya[qtl] += y_;
        }
    }

    #pragma unroll
    for (int qtl = 0; qtl < 4; qtl++) {
        float dv = den[qtl], xv = nxa[qtl], yv = nya[qtl];
        dv += __shfl_down(dv, 32); dv += __shfl_down(dv, 16);
        xv += __shfl_down(xv, 32); xv += __shfl_down(xv, 16);
        yv += __shfl_down(yv, 32); yv += __shfl_down(yv, 16);
        if (lane < 16) {
            int qrow = q0 + qhalf * 64 + qtl * 16 + n16;
            int gi = b * HWN + qrow;
            atomicAdd(&den_g[gi], dv);
            atomicAdd(&nx_g[gi],  xv);
            atomicAdd(&ny_g[gi],  yv);
        }
    }
}

// ---------------------------------------------------------------------------
__global__ __launch_bounds__(256) void finalize_kernel(
    const float* __restrict__ den_g, const float* __restrict__ nx_g,
    const float* __restrict__ ny_g, float* __restrict__ out)
{
    int idx = blockIdx.x * 256 + threadIdx.x;  // b*HW + n
    int b = idx >> 12, n = idx & 4095;
    float inv = 1.0f / den_g[idx];
    out[(size_t)b * 2 * HWN + n]       = nx_g[idx] * inv;
    out[(size_t)b * 2 * HWN + HWN + n] = ny_g[idx] * inv;
}

extern "C" void kernel_launch(void* const* d_in, const int* in_sizes, int n_in,
                              void* d_out, int out_size, void* d_ws, size_t ws_size,
                              hipStream_t stream) {
    const float* feature = (const float*)d_in[0];
    const float* flow    = (const float*)d_in[1];
    const float* q_w     = (const float*)d_in[2];
    const float* q_b     = (const float*)d_in[3];
    const float* k_w     = (const float*)d_in[4];
    const float* k_b     = (const float*)d_in[5];
    float* out = (float*)d_out;

    ushort_t* qbuf = (ushort_t*)d_ws;                     // [NTOK][CC] bf16, frag-major
    ushort_t* kbuf = qbuf + (size_t)NTOK * CC;            // [NTOK][CC] bf16, frag-major
    float* den = (float*)(kbuf + (size_t)NTOK * CC);      // [NTOK]
    float* nx  = den + NTOK;
    float* ny  = nx + NTOK;
    ushort_t* qwb = (ushort_t*)(ny + NTOK);               // [CC][CC] bf16 (pre-scaled)
    ushort_t* kwb = qwb + (size_t)CC * CC;                // [CC][CC] bf16
    ushort_t* fbuf = kwb + (size_t)CC * CC;               // [NTOK][CC] bf16 token-major

    prep_kernel<<<1088, 256, 0, stream>>>(feature, q_w, k_w, fbuf, qwb, kwb, den);
    proj_kernel<<<1024, 256, 0, stream>>>(fbuf, qwb, kwb, q_b, k_b, qbuf, kbuf);
    attn_kernel<<<1024, 256, 0, stream>>>(qbuf, kbuf, flow, den, nx, ny);
    finalize_kernel<<<64, 256, 0, stream>>>(den, nx, ny, out);
}

// Round 6
// 143.386 us; speedup vs baseline: 1.1135x; 1.0186x over previous
//
// Round 6 submission == round 5 kernel, resubmitted verbatim: round 5 failed
// with "MI355X container failed twice" (infra acquire failure, no pytest /
// counters) — the v5 retile was never measured. Structure is the verified v4
// dataflow with a 64-q x 1024-key block (40 KB LDS -> 4 blocks/CU).
#include <hip/hip_runtime.h>
#include <math.h>

#define BB 4
#define CC 256
#define HWN 4096
#define NTOK 16384                 // BB*HWN
#define SCQ 0.09016844136f         // (1/sqrt(256)) * log2(e)

typedef __attribute__((ext_vector_type(8))) short short8;
typedef __attribute__((ext_vector_type(4))) float f32x4;
typedef unsigned short ushort_t;

__device__ __forceinline__ ushort_t f2bf(float f) {
    unsigned int u = __float_as_uint(f);
    unsigned int r = (u + 0x7FFFu + ((u >> 16) & 1u)) >> 16;   // RNE
    return (ushort_t)r;
}
__device__ __forceinline__ unsigned int pack2(float a, float b) {
    return (unsigned int)f2bf(a) | ((unsigned int)f2bf(b) << 16);
}
__device__ __forceinline__ float fexp2(float x) {
#if __has_builtin(__builtin_amdgcn_exp2f)
    return __builtin_amdgcn_exp2f(x);     // single v_exp_f32
#else
    return exp2f(x);
#endif
}

// ---------------------------------------------------------------------------
// Kernel 0: prep. Blocks 0..1023: transpose feature [C][HW] fp32 -> fbuf
// [HW][C] bf16 (64x64 tiles via LDS). Blocks 1024..1087: convert q_w
// (pre-scaled by SCQ) and k_w to bf16; zero den/nx/ny.
// ---------------------------------------------------------------------------
__global__ __launch_bounds__(256) void prep_kernel(
    const float* __restrict__ feature,
    const float* __restrict__ q_w, const float* __restrict__ k_w,
    ushort_t* __restrict__ fbuf,
    ushort_t* __restrict__ qwb, ushort_t* __restrict__ kwb,
    float* __restrict__ zbuf)
{
    int bid = blockIdx.x;
    int tid = threadIdx.x;

    if (bid >= 1024) {                       // weight convert + zero
        int t = (bid - 1024) * 256 + tid;    // 0..16383
        float4 q4 = *(const float4*)&q_w[(size_t)t * 4];
        float4 k4 = *(const float4*)&k_w[(size_t)t * 4];
        unsigned long long qo = (unsigned long long)pack2(q4.x * SCQ, q4.y * SCQ)
                              | ((unsigned long long)pack2(q4.z * SCQ, q4.w * SCQ) << 32);
        unsigned long long ko = (unsigned long long)pack2(k4.x, k4.y)
                              | ((unsigned long long)pack2(k4.z, k4.w) << 32);
        *(unsigned long long*)&qwb[(size_t)t * 4] = qo;
        *(unsigned long long*)&kwb[(size_t)t * 4] = ko;
        zbuf[t] = 0.f; zbuf[t + NTOK] = 0.f; zbuf[t + 2 * NTOK] = 0.f;
        return;
    }

    // transpose tile: b (0..3), cch (0..3), nch (0..63)
    int b   = bid >> 8;
    int rem = bid & 255;
    int cch = rem >> 6;
    int nch = rem & 63;

    __shared__ float lsA[64][69];            // [c][n] fp32, stride 69

    int cl = tid >> 2, tg = (tid & 3) * 16;
    const float* src = feature + (size_t)(b * CC + cch * 64 + cl) * HWN + nch * 64 + tg;
    *(float4*)&lsA[cl][tg]      = *(const float4*)(src);
    *(float4*)&lsA[cl][tg + 4]  = *(const float4*)(src + 4);
    *(float4*)&lsA[cl][tg + 8]  = *(const float4*)(src + 8);
    *(float4*)&lsA[cl][tg + 12] = *(const float4*)(src + 12);
    __syncthreads();

    int tokw = tid >> 2, c16 = (tid & 3) * 16;
    unsigned int u[8];
    #pragma unroll
    for (int j = 0; j < 8; j++)
        u[j] = pack2(lsA[c16 + 2 * j][tokw], lsA[c16 + 2 * j + 1][tokw]);
    size_t orow = (size_t)(b * HWN + nch * 64 + tokw) * CC + cch * 64 + c16;
    *(uint4*)&fbuf[orow]     = *(uint4*)&u[0];
    *(uint4*)&fbuf[orow + 8] = *(uint4*)&u[4];
}

// ---------------------------------------------------------------------------
// Projection: register GEMM, no LDS/barriers. Block = 64 tokens x 64-d
// quarter. OUTPUT IS FRAGMENT-GRANULE MAJOR: granule g(b,tile16,kc,quad,n16)
// = X[tile*16+n16][kc*32+quad*8 .. +8] stored at byte ((b*256+tile)*512 +
// kc*64 + quad*16 + n16)*16.
// ---------------------------------------------------------------------------
__global__ __launch_bounds__(256, 2) void proj_kernel(
    const ushort_t* __restrict__ fbuf,
    const ushort_t* __restrict__ qwb, const ushort_t* __restrict__ kwb,
    const float* __restrict__ q_bias, const float* __restrict__ k_bias,
    ushort_t* __restrict__ qb, ushort_t* __restrict__ kb)
{
    int id = blockIdx.x;
    int dh = id >> 8;                 // 0..3 d-quarter
    int inner = id & 255;
    int b   = inner & 3;
    int tch = inner >> 2;             // 0..63
    int tok0 = tch * 64;

    int t = threadIdx.x, w = t >> 6, lane = t & 63;
    int n16 = lane & 15, quad = lane >> 4;

    int d0 = dh * 64 + w * 16;

    short8 aq[8], ak[8];
    #pragma unroll
    for (int kc = 0; kc < 8; kc++) {
        size_t off = (size_t)(d0 + n16) * CC + kc * 32 + quad * 8;
        aq[kc] = *(const short8*)&qwb[off];
        ak[kc] = *(const short8*)&kwb[off];
    }
    float bqv[4], bkv[4];
    #pragma unroll
    for (int r = 0; r < 4; r++) {
        bqv[r] = q_bias[d0 + quad * 4 + r] * SCQ;
        bkv[r] = k_bias[d0 + quad * 4 + r];
    }

    // fragment-granule store indices (loop-invariant parts)
    int kcq   = d0 >> 5;                          // kc of the granule
    int quadA = ((d0 >> 4) & 1) * 2 + (quad >> 1);// quad of the granule
    int halfo = quad & 1;                         // which 8B half

    #pragma unroll
    for (int tokt = 0; tokt < 4; tokt++) {
        size_t trow = (size_t)(b * HWN + tok0 + tokt * 16 + n16) * CC;
        short8 bf[8];
        #pragma unroll
        for (int kc = 0; kc < 8; kc++)
            bf[kc] = *(const short8*)&fbuf[trow + kc * 32 + quad * 8];
        f32x4 accq = (f32x4){0.f, 0.f, 0.f, 0.f};
        f32x4 acck = (f32x4){0.f, 0.f, 0.f, 0.f};
        #pragma unroll
        for (int kc = 0; kc < 8; kc++) {
            accq = __builtin_amdgcn_mfma_f32_16x16x32_bf16(aq[kc], bf[kc], accq, 0, 0, 0);
            acck = __builtin_amdgcn_mfma_f32_16x16x32_bf16(ak[kc], bf[kc], acck, 0, 0, 0);
        }
        ushort4 oq, ok;
        oq.x = f2bf(accq[0] + bqv[0]); oq.y = f2bf(accq[1] + bqv[1]);
        oq.z = f2bf(accq[2] + bqv[2]); oq.w = f2bf(accq[3] + bqv[3]);
        ok.x = f2bf(acck[0] + bkv[0]); ok.y = f2bf(acck[1] + bkv[1]);
        ok.z = f2bf(acck[2] + bkv[2]); ok.w = f2bf(acck[3] + bkv[3]);
        int tt_tile = tch * 4 + tokt;
        size_t gbyte = (((size_t)(b * 256 + tt_tile) * 512) + kcq * 64 + quadA * 16 + n16) * 16
                       + halfo * 8;
        *(ushort4*)((char*)qb + gbyte) = oq;
        *(ushort4*)((char*)kb + gbyte) = ok;
    }
}

// ---------------------------------------------------------------------------
// Barrier-free flash attention v5. Block = (b, 64-q, 1024-key), 4 waves =
// 4 key-quarters; wave = 64 q x 256 keys. LDS: Q 32KB + flow 8KB = 40KB ->
// 4 blocks/CU (16 waves/CU, 2x v4 residency -- the v4 limiter). Q staged
// linearly once (single prologue barrier), read lane-contiguous stride-16B
// (conflict-free). K streamed L2->regs per 32-key round, 1KB/inst coalesced.
// mfma(K,Q): lane owns 4 key-rows x 1 q-col; den/nx/ny = 12 regs.
// No K-loop barriers; partials merged via atomics.
// ---------------------------------------------------------------------------
__global__ __launch_bounds__(256, 2) void attn_kernel(
    const ushort_t* __restrict__ qb, const ushort_t* __restrict__ kb,
    const float* __restrict__ flow,
    float* __restrict__ den_g, float* __restrict__ nx_g, float* __restrict__ ny_g)
{
    int id = (blockIdx.x & 7) * 128 + (blockIdx.x >> 3);   // bijective XCD swizzle
    int qt = id & 63; id >>= 6;       // 64 q-tiles of 64 rows
    int sr = id & 3;  id >>= 2;       // 4 key ranges of 1024
    int b = id;

    int t = threadIdx.x;
    int w = t >> 6, lane = t & 63;
    int n16 = lane & 15, quad = lane >> 4;

    int q0 = qt * 64;
    int s_beg = sr * 1024;

    __shared__ __align__(16) ushort_t qlds[16384];   // 32 KB: 4 q-tiles, frag-major
    __shared__ float lflow[2048];                    // 1024 vx + 1024 vy

    const float* fx = flow + (size_t)b * 2 * HWN;
    const float* fy = fx + HWN;
    #pragma unroll
    for (int i = 0; i < 4; i++) {
        lflow[t + i * 256]        = fx[s_beg + t + i * 256];
        lflow[1024 + t + i * 256] = fy[s_beg + t + i * 256];
    }

    // stage Q block (4 tiles x 512 granules x 16B = 32KB), linear copy
    {
        const char* qsrc = (const char*)qb + ((size_t)(b * 256 + (q0 >> 4)) * 512) * 16;
        char* qdst = (char*)qlds;
        #pragma unroll
        for (int i = 0; i < 8; i++)
            __builtin_amdgcn_global_load_lds(
                (const __attribute__((address_space(1))) unsigned int*)(qsrc + (i * 256 + t) * 16),
                (__attribute__((address_space(3))) unsigned int*)(qdst + (i * 256 + t) * 16),
                16, 0, 0);
    }
    __syncthreads();   // only barrier: Q + flow staged

    // K granule base for this wave's 256-key quarter
    const char* kbase = (const char*)kb
        + ((size_t)(b * 256 + (s_beg >> 4) + w * 16) * 512 + lane) * 16;
    const char* qldsb = (const char*)qlds + (size_t)lane * 16;

    float den[4], nxa[4], nya[4];
    #pragma unroll
    for (int i = 0; i < 4; i++) { den[i] = 0.f; nxa[i] = 0.f; nya[i] = 0.f; }

    for (int round = 0; round < 8; round++) {
        short8 kf0[8], kf1[8];
        #pragma unroll
        for (int kc = 0; kc < 8; kc++) {
            kf0[kc] = *(const short8*)(kbase + (round * 2 + 0) * 8192 + kc * 1024);
            kf1[kc] = *(const short8*)(kbase + (round * 2 + 1) * 8192 + kc * 1024);
        }
        int klbase = w * 256 + round * 32 + quad * 4;
        f32x4 vx0 = *(const f32x4*)&lflow[klbase];
        f32x4 vx1 = *(const f32x4*)&lflow[klbase + 16];
        f32x4 vy0 = *(const f32x4*)&lflow[1024 + klbase];
        f32x4 vy1 = *(const f32x4*)&lflow[1024 + klbase + 16];

        #pragma unroll
        for (int qtl = 0; qtl < 4; qtl++) {
            f32x4 a0 = (f32x4){0.f, 0.f, 0.f, 0.f};
            f32x4 a1 = (f32x4){0.f, 0.f, 0.f, 0.f};
            #pragma unroll
            for (int kc = 0; kc < 8; kc++) {
                short8 qf = *(const short8*)(qldsb + qtl * 8192 + kc * 1024);
                a0 = __builtin_amdgcn_mfma_f32_16x16x32_bf16(kf0[kc], qf, a0, 0, 0, 0);
                a1 = __builtin_amdgcn_mfma_f32_16x16x32_bf16(kf1[kc], qf, a1, 0, 0, 0);
            }
            float d_ = 0.f, x_ = 0.f, y_ = 0.f;
            #pragma unroll
            for (int r = 0; r < 4; r++) {
                float p0 = fexp2(a0[r]);
                float p1 = fexp2(a1[r]);
                d_ += p0 + p1;
                x_ = fmaf(p0, vx0[r], x_); x_ = fmaf(p1, vx1[r], x_);
                y_ = fmaf(p0, vy0[r], y_); y_ = fmaf(p1, vy1[r], y_);
            }
            den[qtl] += d_; nxa[qtl] += x_; nya[qtl] += y_;
        }
    }

    #pragma unroll
    for (int qtl = 0; qtl < 4; qtl++) {
        float dv = den[qtl], xv = nxa[qtl], yv = nya[qtl];
        dv += __shfl_down(dv, 32); dv += __shfl_down(dv, 16);
        xv += __shfl_down(xv, 32); xv += __shfl_down(xv, 16);
        yv += __shfl_down(yv, 32); yv += __shfl_down(yv, 16);
        if (lane < 16) {
            int qrow = q0 + qtl * 16 + n16;
            int gi = b * HWN + qrow;
            atomicAdd(&den_g[gi], dv);
            atomicAdd(&nx_g[gi],  xv);
            atomicAdd(&ny_g[gi],  yv);
        }
    }
}

// ---------------------------------------------------------------------------
__global__ __launch_bounds__(256) void finalize_kernel(
    const float* __restrict__ den_g, const float* __restrict__ nx_g,
    const float* __restrict__ ny_g, float* __restrict__ out)
{
    int idx = blockIdx.x * 256 + threadIdx.x;  // b*HW + n
    int b = idx >> 12, n = idx & 4095;
    float inv = 1.0f / den_g[idx];
    out[(size_t)b * 2 * HWN + n]       = nx_g[idx] * inv;
    out[(size_t)b * 2 * HWN + HWN + n] = ny_g[idx] * inv;
}

extern "C" void kernel_launch(void* const* d_in, const int* in_sizes, int n_in,
                              void* d_out, int out_size, void* d_ws, size_t ws_size,
                              hipStream_t stream) {
    const float* feature = (const float*)d_in[0];
    const float* flow    = (const float*)d_in[1];
    const float* q_w     = (const float*)d_in[2];
    const float* q_b     = (const float*)d_in[3];
    const float* k_w     = (const float*)d_in[4];
    const float* k_b     = (const float*)d_in[5];
    float* out = (float*)d_out;

    ushort_t* qbuf = (ushort_t*)d_ws;                     // [NTOK][CC] bf16, frag-major
    ushort_t* kbuf = qbuf + (size_t)NTOK * CC;            // [NTOK][CC] bf16, frag-major
    float* den = (float*)(kbuf + (size_t)NTOK * CC);      // [NTOK]
    float* nx  = den + NTOK;
    float* ny  = nx + NTOK;
    ushort_t* qwb = (ushort_t*)(ny + NTOK);               // [CC][CC] bf16 (pre-scaled)
    ushort_t* kwb = qwb + (size_t)CC * CC;                // [CC][CC] bf16
    ushort_t* fbuf = kwb + (size_t)CC * CC;               // [NTOK][CC] bf16 token-major

    prep_kernel<<<1088, 256, 0, stream>>>(feature, q_w, k_w, fbuf, qwb, kwb, den);
    proj_kernel<<<1024, 256, 0, stream>>>(fbuf, qwb, kwb, q_b, k_b, qbuf, kbuf);
    attn_kernel<<<1024, 256, 0, stream>>>(qbuf, kbuf, flow, den, nx, ny);
    finalize_kernel<<<64, 256, 0, stream>>>(den, nx, ny, out);
}